// Round 1
// baseline (1880.672 us; speedup 1.0000x reference)
//
#include <hip/hip_runtime.h>

// NNPredictor: edge MLP with BN folded into weights.
// Pipeline: hist -> e/h stats -> fold BN0 into W1 -> P = h@W1hd' (per node)
//           -> L1: a1 = ReLU(P_s[src]+P_d[dst]+e@W1e'+b1') + BN1 stats
//           -> fold BN1 into W2 -> L2: a2 = ReLU(a1@W2'+b2') + BN2 stats
//           -> fold BN2 into W3 -> L3: out = a2.w3' + b3'
// All GEMMs: bf16 MFMA 16x16x32, fp32 accum. ws usage ~667 MB.

#define N_EDGES 800000
#define N_NODES 50000

typedef __attribute__((ext_vector_type(8))) short bf8_t;
typedef __attribute__((ext_vector_type(4))) float f4_t;

__device__ __forceinline__ unsigned short f2bf(float f) {
    unsigned int u = __builtin_bit_cast(unsigned int, f);
    u += 0x7FFFu + ((u >> 16) & 1u);
    return (unsigned short)(u >> 16);
}
__device__ __forceinline__ float bf2f(unsigned short s) {
    unsigned int u = ((unsigned int)s) << 16;
    return __builtin_bit_cast(float, u);
}
__device__ __forceinline__ bf8_t load8f_bf(const float* p) {
    f4_t x = *(const f4_t*)p;
    f4_t y = *(const f4_t*)(p + 4);
    bf8_t r;
    r[0] = (short)f2bf(x[0]); r[1] = (short)f2bf(x[1]);
    r[2] = (short)f2bf(x[2]); r[3] = (short)f2bf(x[3]);
    r[4] = (short)f2bf(y[0]); r[5] = (short)f2bf(y[1]);
    r[6] = (short)f2bf(y[2]); r[7] = (short)f2bf(y[3]);
    return r;
}

__global__ __launch_bounds__(256) void k_hist(const int* __restrict__ src, const int* __restrict__ dst,
                                              int* __restrict__ cs, int* __restrict__ cd) {
    int i = blockIdx.x * 256 + threadIdx.x;
    if (i < N_EDGES) {
        atomicAdd(&cs[src[i]], 1);
        atomicAdd(&cd[dst[i]], 1);
    }
}

__global__ __launch_bounds__(256) void k_estats(const float* __restrict__ e,
                                                float* __restrict__ sum, float* __restrict__ sq) {
    const int tid = threadIdx.x;
    const int c = tid & 63, g = tid >> 6;
    float s = 0.f, q = 0.f;
    for (int i = blockIdx.x * 4 + g; i < N_EDGES; i += gridDim.x * 4) {
        float v = e[(size_t)i * 64 + c];
        s += v; q += v * v;
    }
    __shared__ float red[256];
    red[tid] = s; __syncthreads();
    if (tid < 64) atomicAdd(&sum[256 + tid], red[tid] + red[tid + 64] + red[tid + 128] + red[tid + 192]);
    __syncthreads();
    red[tid] = q; __syncthreads();
    if (tid < 64) atomicAdd(&sq[256 + tid], red[tid] + red[tid + 64] + red[tid + 128] + red[tid + 192]);
}

__global__ __launch_bounds__(256) void k_hstats(const float* __restrict__ h,
                                                const int* __restrict__ cs, const int* __restrict__ cd,
                                                float* __restrict__ sum, float* __restrict__ sq) {
    const int tid = threadIdx.x;
    const int c = tid & 127, g = tid >> 7;
    float ss = 0.f, qs = 0.f, sd = 0.f, qd = 0.f;
    for (int n = blockIdx.x * 2 + g; n < N_NODES; n += gridDim.x * 2) {
        float v = h[(size_t)n * 128 + c];
        float a = (float)cs[n], b = (float)cd[n];
        ss += a * v; qs += a * v * v;
        sd += b * v; qd += b * v * v;
    }
    __shared__ float red[256];
    red[tid] = ss; __syncthreads();
    if (tid < 128) atomicAdd(&sum[tid], red[tid] + red[tid + 128]);
    __syncthreads();
    red[tid] = qs; __syncthreads();
    if (tid < 128) atomicAdd(&sq[tid], red[tid] + red[tid + 128]);
    __syncthreads();
    red[tid] = sd; __syncthreads();
    if (tid < 128) atomicAdd(&sum[128 + tid], red[tid] + red[tid + 128]);
    __syncthreads();
    red[tid] = qd; __syncthreads();
    if (tid < 128) atomicAdd(&sq[128 + tid], red[tid] + red[tid + 128]);
}

__global__ __launch_bounds__(320) void k_fold0(const float* __restrict__ sum, const float* __restrict__ sq,
        const float* __restrict__ g0, const float* __restrict__ b0,
        float* __restrict__ scale0, float* __restrict__ shift0) {
    int j = threadIdx.x;
    if (j < 320) {
        const float invE = 1.f / (float)N_EDGES;
        float mu = sum[j] * invE;
        float var = sq[j] * invE - mu * mu;
        float sc = g0[j] * rsqrtf(var + 1e-5f);
        scale0[j] = sc;
        shift0[j] = b0[j] - mu * sc;
    }
}

__global__ __launch_bounds__(320) void k_foldW1(const float* __restrict__ W1, const float* __restrict__ b1,
        const float* __restrict__ scale0, const float* __restrict__ shift0,
        unsigned short* __restrict__ W1s, unsigned short* __restrict__ W1d,
        unsigned short* __restrict__ W1e, float* __restrict__ b1p) {
    __shared__ float sc[320], sh[320];
    const int tid = threadIdx.x;
    if (tid < 320) { sc[tid] = scale0[tid]; sh[tid] = shift0[tid]; }
    __syncthreads();
    if (tid < 256) {
        float acc = b1[tid];
        const float* wr = W1 + (size_t)tid * 320;
        for (int j = 0; j < 320; ++j) {
            float wv = wr[j];
            acc += wv * sh[j];
            unsigned short wb = f2bf(wv * sc[j]);
            if (j < 128) W1s[tid * 128 + j] = wb;
            else if (j < 256) W1d[tid * 128 + (j - 128)] = wb;
            else W1e[tid * 64 + (j - 256)] = wb;
        }
        b1p[tid] = acc;
    }
}

// P_{s,d} = h @ W1{s,d}'^T : M=50000 (tile 64), N=256, K=128
__global__ __launch_bounds__(256) void k_P(const float* __restrict__ h,
        const unsigned short* __restrict__ W1s, const unsigned short* __restrict__ W1d,
        unsigned short* __restrict__ Ps, unsigned short* __restrict__ Pd) {
    const int tid = threadIdx.x;
    const int w = tid >> 6, lane = tid & 63, quad = lane >> 4, l15 = lane & 15;
    const unsigned short* W = blockIdx.y ? W1d : W1s;
    unsigned short* P = blockIdx.y ? Pd : Ps;
    int rm = blockIdx.x * 64 + w * 16 + l15;
    if (rm >= N_NODES) rm = N_NODES - 1;
    const float* arow = h + (size_t)rm * 128;
    f4_t acc[16];
#pragma unroll
    for (int nt = 0; nt < 16; ++nt) acc[nt] = (f4_t){0.f, 0.f, 0.f, 0.f};
#pragma unroll
    for (int ks = 0; ks < 4; ++ks) {
        bf8_t a = load8f_bf(arow + ks * 32 + quad * 8);
#pragma unroll
        for (int nt = 0; nt < 16; ++nt) {
            bf8_t b = *(const bf8_t*)(W + (size_t)(nt * 16 + l15) * 128 + ks * 32 + quad * 8);
            acc[nt] = __builtin_amdgcn_mfma_f32_16x16x32_bf16(a, b, acc[nt], 0, 0, 0);
        }
    }
    const int rb = blockIdx.x * 64 + w * 16 + quad * 4;
#pragma unroll
    for (int nt = 0; nt < 16; ++nt) {
#pragma unroll
        for (int r = 0; r < 4; ++r) {
            int row = rb + r;
            if (row < N_NODES) P[(size_t)row * 256 + nt * 16 + l15] = f2bf(acc[nt][r]);
        }
    }
}

// a1 = ReLU(Ps[src]+Pd[dst] + e@W1e'^T + b1'); accumulate BN1 col sums/sumsq.
__global__ __launch_bounds__(256) void k_L1(const float* __restrict__ e,
        const int* __restrict__ src, const int* __restrict__ dst,
        const unsigned short* __restrict__ Ps, const unsigned short* __restrict__ Pd,
        const unsigned short* __restrict__ W1e, const float* __restrict__ b1p,
        unsigned short* __restrict__ a1, float* __restrict__ slots) {
    __shared__ unsigned short Pl[64 * 256];
    __shared__ int idx[128];
    __shared__ float bn[512];
    const int tid = threadIdx.x;
    const int w = tid >> 6, lane = tid & 63, quad = lane >> 4, l15 = lane & 15;
    const size_t base = (size_t)blockIdx.x * 64;
    if (tid < 128) idx[tid] = (tid < 64) ? src[base + tid] : dst[base + tid - 64];
    bn[tid] = 0.f; bn[tid + 256] = 0.f;
    __syncthreads();
    {   // gather Ps+Pd rows (pre-summed, bf16) into LDS
        const int rown = tid >> 5, chunk = tid & 31;
#pragma unroll
        for (int p = 0; p < 8; ++p) {
            const int row = p * 8 + rown;
            uint4 sv = *(const uint4*)(Ps + (size_t)idx[row] * 256 + chunk * 8);
            uint4 dv = *(const uint4*)(Pd + (size_t)idx[row + 64] * 256 + chunk * 8);
            const unsigned short* su = (const unsigned short*)&sv;
            const unsigned short* du = (const unsigned short*)&dv;
            uint4 ov;
            unsigned short* ou = (unsigned short*)&ov;
#pragma unroll
            for (int j = 0; j < 8; ++j) ou[j] = f2bf(bf2f(su[j]) + bf2f(du[j]));
            *(uint4*)(Pl + row * 256 + chunk * 8) = ov;
        }
    }
    f4_t acc[16];
#pragma unroll
    for (int nt = 0; nt < 16; ++nt) acc[nt] = (f4_t){0.f, 0.f, 0.f, 0.f};
    const float* erow = e + (base + w * 16 + l15) * 64;
#pragma unroll
    for (int ks = 0; ks < 2; ++ks) {
        bf8_t a = load8f_bf(erow + ks * 32 + quad * 8);
#pragma unroll
        for (int nt = 0; nt < 16; ++nt) {
            bf8_t b = *(const bf8_t*)(W1e + (size_t)(nt * 16 + l15) * 64 + ks * 32 + quad * 8);
            acc[nt] = __builtin_amdgcn_mfma_f32_16x16x32_bf16(a, b, acc[nt], 0, 0, 0);
        }
    }
    __syncthreads();
    const int rl0 = w * 16 + quad * 4;
#pragma unroll
    for (int nt = 0; nt < 16; ++nt) {
        const int col = nt * 16 + l15;
        const float bb = b1p[col];
        float s = 0.f, q = 0.f;
#pragma unroll
        for (int r = 0; r < 4; ++r) {
            const int rl = rl0 + r;
            float v = acc[nt][r] + bf2f(Pl[rl * 256 + col]) + bb;
            v = fmaxf(v, 0.f);
            a1[(base + rl) * 256 + col] = f2bf(v);
            s += v; q += v * v;
        }
        s += __shfl_xor(s, 16); s += __shfl_xor(s, 32);
        q += __shfl_xor(q, 16); q += __shfl_xor(q, 32);
        if (quad == 0) { atomicAdd(&bn[col], s); atomicAdd(&bn[256 + col], q); }
    }
    __syncthreads();
    float* sl = slots + (size_t)(blockIdx.x & 63) * 512;
    atomicAdd(&sl[tid], bn[tid]);
    atomicAdd(&sl[tid + 256], bn[tid + 256]);
}

__global__ __launch_bounds__(256) void k_fold1(const float* __restrict__ slots,
        const float* __restrict__ g1, const float* __restrict__ b1n,
        const float* __restrict__ W2, const float* __restrict__ b2,
        unsigned short* __restrict__ W2p, float* __restrict__ b2p) {
    __shared__ float sc[256], sh[256];
    const int tid = threadIdx.x;
    float S = 0.f, Q = 0.f;
    for (int s = 0; s < 64; ++s) { S += slots[s * 512 + tid]; Q += slots[s * 512 + 256 + tid]; }
    const float invE = 1.f / (float)N_EDGES;
    float mu = S * invE;
    float var = Q * invE - mu * mu;
    float scl = g1[tid] * rsqrtf(var + 1e-5f);
    sc[tid] = scl; sh[tid] = b1n[tid] - mu * scl;
    __syncthreads();
    if (tid < 128) {
        float acc = b2[tid];
        const float* wr = W2 + (size_t)tid * 256;
        for (int j = 0; j < 256; ++j) {
            float wv = wr[j];
            acc += wv * sh[j];
            W2p[tid * 256 + j] = f2bf(wv * sc[j]);
        }
        b2p[tid] = acc;
    }
}

// a2 = ReLU(a1 @ W2'^T + b2'); accumulate BN2 stats. M tile 64, N=128, K=256.
__global__ __launch_bounds__(256) void k_L2(const unsigned short* __restrict__ a1,
        const unsigned short* __restrict__ W2p, const float* __restrict__ b2p,
        unsigned short* __restrict__ a2, float* __restrict__ slots) {
    __shared__ float bn[256];
    const int tid = threadIdx.x;
    const int w = tid >> 6, lane = tid & 63, quad = lane >> 4, l15 = lane & 15;
    const size_t base = (size_t)blockIdx.x * 64;
    bn[tid] = 0.f;
    const unsigned short* arow = a1 + (base + w * 16 + l15) * 256;
    f4_t acc[8];
#pragma unroll
    for (int nt = 0; nt < 8; ++nt) acc[nt] = (f4_t){0.f, 0.f, 0.f, 0.f};
#pragma unroll
    for (int ks = 0; ks < 8; ++ks) {
        bf8_t a = *(const bf8_t*)(arow + ks * 32 + quad * 8);
#pragma unroll
        for (int nt = 0; nt < 8; ++nt) {
            bf8_t b = *(const bf8_t*)(W2p + (size_t)(nt * 16 + l15) * 256 + ks * 32 + quad * 8);
            acc[nt] = __builtin_amdgcn_mfma_f32_16x16x32_bf16(a, b, acc[nt], 0, 0, 0);
        }
    }
    __syncthreads();
    const int rl0 = w * 16 + quad * 4;
#pragma unroll
    for (int nt = 0; nt < 8; ++nt) {
        const int col = nt * 16 + l15;
        const float bb = b2p[col];
        float s = 0.f, q = 0.f;
#pragma unroll
        for (int r = 0; r < 4; ++r) {
            float v = acc[nt][r] + bb;
            v = fmaxf(v, 0.f);
            a2[(base + rl0 + r) * 128 + col] = f2bf(v);
            s += v; q += v * v;
        }
        s += __shfl_xor(s, 16); s += __shfl_xor(s, 32);
        q += __shfl_xor(q, 16); q += __shfl_xor(q, 32);
        if (quad == 0) { atomicAdd(&bn[col], s); atomicAdd(&bn[128 + col], q); }
    }
    __syncthreads();
    atomicAdd(&slots[(size_t)(blockIdx.x & 63) * 256 + tid], bn[tid]);
}

__global__ __launch_bounds__(128) void k_fold2(const float* __restrict__ slots,
        const float* __restrict__ g2, const float* __restrict__ b2n,
        const float* __restrict__ W3, const float* __restrict__ b3,
        float* __restrict__ w3p, float* __restrict__ b3p) {
    __shared__ float red[128];
    const int tid = threadIdx.x;
    float S = 0.f, Q = 0.f;
    for (int s = 0; s < 64; ++s) { S += slots[s * 256 + tid]; Q += slots[s * 256 + 128 + tid]; }
    const float invE = 1.f / (float)N_EDGES;
    float mu = S * invE;
    float var = Q * invE - mu * mu;
    float scl = g2[tid] * rsqrtf(var + 1e-5f);
    float shf = b2n[tid] - mu * scl;
    w3p[tid] = W3[tid] * scl;
    red[tid] = W3[tid] * shf;
    __syncthreads();
    for (int st = 64; st > 0; st >>= 1) {
        if (tid < st) red[tid] += red[tid + st];
        __syncthreads();
    }
    if (tid == 0) b3p[0] = b3[0] + red[0];
}

__global__ __launch_bounds__(256) void k_L3(const unsigned short* __restrict__ a2,
        const float* __restrict__ w3p, const float* __restrict__ b3p, float* __restrict__ out) {
    __shared__ float wl[128];
    const int tid = threadIdx.x;
    if (tid < 128) wl[tid] = w3p[tid];
    __syncthreads();
    const size_t i = (size_t)blockIdx.x * 256 + tid;
    const unsigned short* row = a2 + i * 128;
    float s = b3p[0];
#pragma unroll
    for (int c = 0; c < 128; c += 8) {
        uint4 u = *(const uint4*)(row + c);
        const unsigned short* us = (const unsigned short*)&u;
#pragma unroll
        for (int j = 0; j < 8; ++j) s += bf2f(us[j]) * wl[c + j];
    }
    out[i] = s;
}

extern "C" void kernel_launch(void* const* d_in, const int* in_sizes, int n_in,
                              void* d_out, int out_size, void* d_ws, size_t ws_size,
                              hipStream_t stream) {
    (void)in_sizes; (void)n_in; (void)out_size; (void)ws_size;
    const float* h   = (const float*)d_in[0];
    const float* e   = (const float*)d_in[1];
    const int*   src = (const int*)d_in[2];
    const int*   dst = (const int*)d_in[3];
    const float* bn0_g = (const float*)d_in[4];
    const float* bn0_b = (const float*)d_in[5];
    const float* W1 = (const float*)d_in[6];
    const float* b1 = (const float*)d_in[7];
    const float* bn1_g = (const float*)d_in[8];
    const float* bn1_b = (const float*)d_in[9];
    const float* W2 = (const float*)d_in[10];
    const float* b2 = (const float*)d_in[11];
    const float* bn2_g = (const float*)d_in[12];
    const float* bn2_b = (const float*)d_in[13];
    const float* W3 = (const float*)d_in[14];
    const float* b3 = (const float*)d_in[15];

    char* ws = (char*)d_ws;
    size_t off = 0;
    auto alloc = [&](size_t bytes) { char* p = ws + off; off += (bytes + 255) & ~(size_t)255; return p; };
    int*   cnt_s = (int*)alloc((size_t)N_NODES * 4);
    int*   cnt_d = (int*)alloc((size_t)N_NODES * 4);
    float* bn0_sum = (float*)alloc(320 * 4);
    float* bn0_sq  = (float*)alloc(320 * 4);
    float* bn1_slots = (float*)alloc(64 * 512 * 4);
    float* bn2_slots = (float*)alloc(64 * 256 * 4);
    const size_t zero_end = off;
    float* scale0 = (float*)alloc(320 * 4);
    float* shift0 = (float*)alloc(320 * 4);
    unsigned short* W1s = (unsigned short*)alloc(256 * 128 * 2);
    unsigned short* W1d = (unsigned short*)alloc(256 * 128 * 2);
    unsigned short* W1e = (unsigned short*)alloc(256 * 64 * 2);
    float* b1p = (float*)alloc(256 * 4);
    unsigned short* W2p = (unsigned short*)alloc(128 * 256 * 2);
    float* b2p = (float*)alloc(128 * 4);
    float* w3p = (float*)alloc(128 * 4);
    float* b3p = (float*)alloc(4);
    unsigned short* Ps = (unsigned short*)alloc((size_t)N_NODES * 256 * 2);
    unsigned short* Pd = (unsigned short*)alloc((size_t)N_NODES * 256 * 2);
    unsigned short* a1 = (unsigned short*)alloc((size_t)N_EDGES * 256 * 2);
    unsigned short* a2 = (unsigned short*)alloc((size_t)N_EDGES * 128 * 2);

    hipMemsetAsync(d_ws, 0, zero_end, stream);
    k_hist<<<(N_EDGES + 255) / 256, 256, 0, stream>>>(src, dst, cnt_s, cnt_d);
    k_estats<<<256, 256, 0, stream>>>(e, bn0_sum, bn0_sq);
    k_hstats<<<200, 256, 0, stream>>>(h, cnt_s, cnt_d, bn0_sum, bn0_sq);
    k_fold0<<<1, 320, 0, stream>>>(bn0_sum, bn0_sq, bn0_g, bn0_b, scale0, shift0);
    k_foldW1<<<1, 320, 0, stream>>>(W1, b1, scale0, shift0, W1s, W1d, W1e, b1p);
    k_P<<<dim3((N_NODES + 63) / 64, 2), 256, 0, stream>>>(h, W1s, W1d, Ps, Pd);
    k_L1<<<N_EDGES / 64, 256, 0, stream>>>(e, src, dst, Ps, Pd, W1e, b1p, a1, bn1_slots);
    k_fold1<<<1, 256, 0, stream>>>(bn1_slots, bn1_g, bn1_b, W2, b2, W2p, b2p);
    k_L2<<<N_EDGES / 64, 256, 0, stream>>>(a1, W2p, b2p, a2, bn2_slots);
    k_fold2<<<1, 128, 0, stream>>>(bn2_slots, bn2_g, bn2_b, W3, b3, w3p, b3p);
    k_L3<<<N_EDGES / 256, 256, 0, stream>>>(a2, w3p, b3p, (float*)d_out);
}

// Round 2
// 1413.648 us; speedup vs baseline: 1.3304x; 1.3304x over previous
//
#include <hip/hip_runtime.h>

// NNPredictor: edge MLP with BN folded into weights.
// R2: B-in-registers GEMMs, M=256/block, LDS-transpose epilogues, 16B stores.

#define N_EDGES 800000
#define N_NODES 50000

typedef __attribute__((ext_vector_type(8))) short bf8_t;
typedef __attribute__((ext_vector_type(4))) float f4_t;

__device__ __forceinline__ unsigned short f2bf(float f) {
    unsigned int u = __builtin_bit_cast(unsigned int, f);
    u += 0x7FFFu + ((u >> 16) & 1u);
    return (unsigned short)(u >> 16);
}
__device__ __forceinline__ float bf2f(unsigned short s) {
    unsigned int u = ((unsigned int)s) << 16;
    return __builtin_bit_cast(float, u);
}
__device__ __forceinline__ bf8_t load8f_bf(const float* p) {
    f4_t x = *(const f4_t*)p;
    f4_t y = *(const f4_t*)(p + 4);
    bf8_t r;
    r[0] = (short)f2bf(x[0]); r[1] = (short)f2bf(x[1]);
    r[2] = (short)f2bf(x[2]); r[3] = (short)f2bf(x[3]);
    r[4] = (short)f2bf(y[0]); r[5] = (short)f2bf(y[1]);
    r[6] = (short)f2bf(y[2]); r[7] = (short)f2bf(y[3]);
    return r;
}

__global__ __launch_bounds__(256) void k_hist(const int* __restrict__ src, const int* __restrict__ dst,
                                              int* __restrict__ cs, int* __restrict__ cd) {
    int i = blockIdx.x * 256 + threadIdx.x;
    if (i < N_EDGES) {
        atomicAdd(&cs[src[i]], 1);
        atomicAdd(&cd[dst[i]], 1);
    }
}

// e column sums/sumsq, float4 loads: thread covers cols (tid&15)*4..+3, 16 rows/block-iter
__global__ __launch_bounds__(256) void k_estats(const float* __restrict__ e,
                                                float* __restrict__ sum, float* __restrict__ sq) {
    const int tid = threadIdx.x;
    const int x = tid & 15, r = tid >> 4;
    f4_t s = {0.f, 0.f, 0.f, 0.f}, q = {0.f, 0.f, 0.f, 0.f};
    for (size_t i = blockIdx.x * 16 + r; i < N_EDGES; i += (size_t)gridDim.x * 16) {
        f4_t v = *(const f4_t*)(e + i * 64 + x * 4);
        s += v; q += v * v;
    }
    __shared__ float red[128];
    if (tid < 128) red[tid] = 0.f;
    __syncthreads();
#pragma unroll
    for (int j = 0; j < 4; ++j) {
        atomicAdd(&red[x * 4 + j], s[j]);
        atomicAdd(&red[64 + x * 4 + j], q[j]);
    }
    __syncthreads();
    if (tid < 64) atomicAdd(&sum[256 + tid], red[tid]);
    else if (tid < 128) atomicAdd(&sq[256 + tid - 64], red[tid]);
}

__global__ __launch_bounds__(256) void k_hstats(const float* __restrict__ h,
                                                const int* __restrict__ cs, const int* __restrict__ cd,
                                                float* __restrict__ sum, float* __restrict__ sq) {
    const int tid = threadIdx.x;
    const int c = tid & 127, g = tid >> 7;
    float ss = 0.f, qs = 0.f, sd = 0.f, qd = 0.f;
    for (int n = blockIdx.x * 2 + g; n < N_NODES; n += gridDim.x * 2) {
        float v = h[(size_t)n * 128 + c];
        float a = (float)cs[n], b = (float)cd[n];
        ss += a * v; qs += a * v * v;
        sd += b * v; qd += b * v * v;
    }
    __shared__ float red[256];
    red[tid] = ss; __syncthreads();
    if (tid < 128) atomicAdd(&sum[tid], red[tid] + red[tid + 128]);
    __syncthreads();
    red[tid] = qs; __syncthreads();
    if (tid < 128) atomicAdd(&sq[tid], red[tid] + red[tid + 128]);
    __syncthreads();
    red[tid] = sd; __syncthreads();
    if (tid < 128) atomicAdd(&sum[128 + tid], red[tid] + red[tid + 128]);
    __syncthreads();
    red[tid] = qd; __syncthreads();
    if (tid < 128) atomicAdd(&sq[128 + tid], red[tid] + red[tid + 128]);
}

__global__ __launch_bounds__(320) void k_fold0(const float* __restrict__ sum, const float* __restrict__ sq,
        const float* __restrict__ g0, const float* __restrict__ b0,
        float* __restrict__ scale0, float* __restrict__ shift0) {
    int j = threadIdx.x;
    if (j < 320) {
        const float invE = 1.f / (float)N_EDGES;
        float mu = sum[j] * invE;
        float var = sq[j] * invE - mu * mu;
        float sc = g0[j] * rsqrtf(var + 1e-5f);
        scale0[j] = sc;
        shift0[j] = b0[j] - mu * sc;
    }
}

__global__ __launch_bounds__(320) void k_foldW1(const float* __restrict__ W1, const float* __restrict__ b1,
        const float* __restrict__ scale0, const float* __restrict__ shift0,
        unsigned short* __restrict__ W1s, unsigned short* __restrict__ W1d,
        unsigned short* __restrict__ W1e, float* __restrict__ b1p) {
    __shared__ float sc[320], sh[320];
    const int tid = threadIdx.x;
    if (tid < 320) { sc[tid] = scale0[tid]; sh[tid] = shift0[tid]; }
    __syncthreads();
    if (tid < 256) {
        float acc = b1[tid];
        const float* wr = W1 + (size_t)tid * 320;
        for (int j = 0; j < 320; ++j) {
            float wv = wr[j];
            acc += wv * sh[j];
            unsigned short wb = f2bf(wv * sc[j]);
            if (j < 128) W1s[tid * 128 + j] = wb;
            else if (j < 256) W1d[tid * 128 + (j - 128)] = wb;
            else W1e[tid * 64 + (j - 256)] = wb;
        }
        b1p[tid] = acc;
    }
}

// P = h @ W'^T : M=50000 (256/block), N=256, K=128. B in regs, LDS-transpose stores.
__global__ __launch_bounds__(256) void k_P(const float* __restrict__ h,
        const unsigned short* __restrict__ W1s, const unsigned short* __restrict__ W1d,
        unsigned short* __restrict__ Ps, unsigned short* __restrict__ Pd) {
    __shared__ unsigned short tile[16 * 264];
    const int tid = threadIdx.x;
    const int w = tid >> 6, lane = tid & 63, quad = lane >> 4, l15 = lane & 15;
    const unsigned short* W = blockIdx.y ? W1d : W1s;
    unsigned short* P = blockIdx.y ? Pd : Ps;
    const size_t base = (size_t)blockIdx.x * 256;
    bf8_t bfr[4][4];
#pragma unroll
    for (int j = 0; j < 4; ++j) {
        const unsigned short* wp = W + (size_t)((w * 4 + j) * 16 + l15) * 128 + quad * 8;
#pragma unroll
        for (int ks = 0; ks < 4; ++ks) bfr[j][ks] = *(const bf8_t*)(wp + ks * 32);
    }
    const int erow = tid >> 4, ex = tid & 15;
    for (int mc = 0; mc < 16; ++mc) {
        const size_t row0 = base + mc * 16;
        size_t ar = row0 + l15; if (ar >= N_NODES) ar = N_NODES - 1;
        const float* hp = h + ar * 128 + quad * 8;
        bf8_t af[4];
#pragma unroll
        for (int ks = 0; ks < 4; ++ks) af[ks] = load8f_bf(hp + ks * 32);
#pragma unroll
        for (int j = 0; j < 4; ++j) {
            f4_t t = {0.f, 0.f, 0.f, 0.f};
#pragma unroll
            for (int ks = 0; ks < 4; ++ks)
                t = __builtin_amdgcn_mfma_f32_16x16x32_bf16(af[ks], bfr[j][ks], t, 0, 0, 0);
#pragma unroll
            for (int r = 0; r < 4; ++r)
                tile[(quad * 4 + r) * 264 + (w * 4 + j) * 16 + l15] = f2bf(t[r]);
        }
        __syncthreads();
        const size_t orow = row0 + erow;
        if (orow < N_NODES) {
            uint4 v0 = *(const uint4*)(tile + erow * 264 + ex * 16);
            uint4 v1 = *(const uint4*)(tile + erow * 264 + ex * 16 + 8);
            *(uint4*)(P + orow * 256 + ex * 16) = v0;
            *(uint4*)(P + orow * 256 + ex * 16 + 8) = v1;
        }
        __syncthreads();
    }
}

// a1 = ReLU(e@W1e' + Ps[src] + Pd[dst] + b1'); BN1 stats. M=256/block, N=256, K=64.
__global__ __launch_bounds__(256) void k_L1(const float* __restrict__ e,
        const int* __restrict__ src, const int* __restrict__ dst,
        const unsigned short* __restrict__ Ps, const unsigned short* __restrict__ Pd,
        const unsigned short* __restrict__ W1e, const float* __restrict__ b1p,
        unsigned short* __restrict__ a1, float* __restrict__ slots) {
    __shared__ float tile[16 * 260];
    __shared__ float bn[512];
    __shared__ int sIdx[256], dIdx[256];
    const int tid = threadIdx.x;
    const int w = tid >> 6, lane = tid & 63, quad = lane >> 4, l15 = lane & 15;
    const size_t base = (size_t)blockIdx.x * 256;
    bn[tid] = 0.f; bn[256 + tid] = 0.f;
    sIdx[tid] = src[base + tid];
    dIdx[tid] = dst[base + tid];
    bf8_t bfr[4][2];
#pragma unroll
    for (int j = 0; j < 4; ++j) {
        const unsigned short* wp = W1e + (size_t)((w * 4 + j) * 16 + l15) * 64 + quad * 8;
#pragma unroll
        for (int ks = 0; ks < 2; ++ks) bfr[j][ks] = *(const bf8_t*)(wp + ks * 32);
    }
    const int erow = tid >> 4, ex = tid & 15;
    float bias[4][4], sreg[4][4], qreg[4][4];
#pragma unroll
    for (int i = 0; i < 4; ++i) {
        f4_t b4 = *(const f4_t*)(b1p + ex * 4 + 64 * i);
#pragma unroll
        for (int j = 0; j < 4; ++j) { bias[i][j] = b4[j]; sreg[i][j] = 0.f; qreg[i][j] = 0.f; }
    }
    __syncthreads();
    for (int mc = 0; mc < 16; ++mc) {
        const size_t row0 = base + mc * 16;
        const float* ep = e + (row0 + l15) * 64 + quad * 8;
        bf8_t a0 = load8f_bf(ep);
        bf8_t a1f = load8f_bf(ep + 32);
#pragma unroll
        for (int j = 0; j < 4; ++j) {
            f4_t t = {0.f, 0.f, 0.f, 0.f};
            t = __builtin_amdgcn_mfma_f32_16x16x32_bf16(a0, bfr[j][0], t, 0, 0, 0);
            t = __builtin_amdgcn_mfma_f32_16x16x32_bf16(a1f, bfr[j][1], t, 0, 0, 0);
#pragma unroll
            for (int r = 0; r < 4; ++r)
                tile[(quad * 4 + r) * 260 + (w * 4 + j) * 16 + l15] = t[r];
        }
        __syncthreads();
        const int srow = sIdx[mc * 16 + erow], drow = dIdx[mc * 16 + erow];
        const unsigned short* psp = Ps + (size_t)srow * 256;
        const unsigned short* pdp = Pd + (size_t)drow * 256;
        unsigned short* op = a1 + (row0 + erow) * 256;
#pragma unroll
        for (int i = 0; i < 4; ++i) {
            const int c0 = ex * 4 + 64 * i;
            f4_t g = *(const f4_t*)(tile + erow * 260 + c0);
            uint2 su = *(const uint2*)(psp + c0);
            uint2 du = *(const uint2*)(pdp + c0);
            const unsigned short* ss = (const unsigned short*)&su;
            const unsigned short* dd = (const unsigned short*)&du;
            unsigned short ov[4];
#pragma unroll
            for (int j = 0; j < 4; ++j) {
                float v = g[j] + bf2f(ss[j]) + bf2f(dd[j]) + bias[i][j];
                v = fmaxf(v, 0.f);
                ov[j] = f2bf(v);
                sreg[i][j] += v; qreg[i][j] += v * v;
            }
            *(uint2*)(op + c0) = *(const uint2*)ov;
        }
        __syncthreads();
    }
#pragma unroll
    for (int i = 0; i < 4; ++i)
#pragma unroll
        for (int j = 0; j < 4; ++j) {
            const int c = ex * 4 + 64 * i + j;
            atomicAdd(&bn[c], sreg[i][j]);
            atomicAdd(&bn[256 + c], qreg[i][j]);
        }
    __syncthreads();
    float* sl = slots + (size_t)(blockIdx.x & 63) * 512;
    atomicAdd(&sl[tid], bn[tid]);
    atomicAdd(&sl[tid + 256], bn[tid + 256]);
}

__global__ __launch_bounds__(256) void k_fold1(const float* __restrict__ slots,
        const float* __restrict__ g1, const float* __restrict__ b1n,
        const float* __restrict__ W2, const float* __restrict__ b2,
        unsigned short* __restrict__ W2p, float* __restrict__ b2p) {
    __shared__ float sc[256], sh[256];
    const int tid = threadIdx.x;
    float S = 0.f, Q = 0.f;
    for (int s = 0; s < 64; ++s) { S += slots[s * 512 + tid]; Q += slots[s * 512 + 256 + tid]; }
    const float invE = 1.f / (float)N_EDGES;
    float mu = S * invE;
    float var = Q * invE - mu * mu;
    float scl = g1[tid] * rsqrtf(var + 1e-5f);
    sc[tid] = scl; sh[tid] = b1n[tid] - mu * scl;
    __syncthreads();
    if (tid < 128) {
        float acc = b2[tid];
        const float* wr = W2 + (size_t)tid * 256;
        for (int j = 0; j < 256; ++j) {
            float wv = wr[j];
            acc += wv * sh[j];
            W2p[tid * 256 + j] = f2bf(wv * sc[j]);
        }
        b2p[tid] = acc;
    }
}

// a2 = ReLU(a1 @ W2'^T + b2'); BN2 stats. M=256/block, N=128, K=256.
__global__ __launch_bounds__(256) void k_L2(const unsigned short* __restrict__ a1,
        const unsigned short* __restrict__ W2p, const float* __restrict__ b2p,
        unsigned short* __restrict__ a2, float* __restrict__ slots) {
    __shared__ unsigned short tile[16 * 136];
    __shared__ float bn[256];
    const int tid = threadIdx.x;
    const int w = tid >> 6, lane = tid & 63, quad = lane >> 4, l15 = lane & 15;
    const size_t base = (size_t)blockIdx.x * 256;
    bn[tid] = 0.f;
    bf8_t bfr[2][8];
#pragma unroll
    for (int j = 0; j < 2; ++j) {
        const unsigned short* wp = W2p + (size_t)((w * 2 + j) * 16 + l15) * 256 + quad * 8;
#pragma unroll
        for (int ks = 0; ks < 8; ++ks) bfr[j][ks] = *(const bf8_t*)(wp + ks * 32);
    }
    const float bias0 = b2p[(w * 2) * 16 + l15];
    const float bias1 = b2p[(w * 2 + 1) * 16 + l15];
    const int erow = tid >> 4, ecol = (tid & 15) * 8;
    float sreg[8], qreg[8];
#pragma unroll
    for (int j = 0; j < 8; ++j) { sreg[j] = 0.f; qreg[j] = 0.f; }
    for (int mc = 0; mc < 16; ++mc) {
        const size_t row0 = base + mc * 16;
        bf8_t afr[8];
        const unsigned short* ap = a1 + (row0 + l15) * 256 + quad * 8;
#pragma unroll
        for (int ks = 0; ks < 8; ++ks) afr[ks] = *(const bf8_t*)(ap + ks * 32);
        f4_t acc0 = {0.f, 0.f, 0.f, 0.f}, acc1 = {0.f, 0.f, 0.f, 0.f};
#pragma unroll
        for (int ks = 0; ks < 8; ++ks) {
            acc0 = __builtin_amdgcn_mfma_f32_16x16x32_bf16(afr[ks], bfr[0][ks], acc0, 0, 0, 0);
            acc1 = __builtin_amdgcn_mfma_f32_16x16x32_bf16(afr[ks], bfr[1][ks], acc1, 0, 0, 0);
        }
#pragma unroll
        for (int r = 0; r < 4; ++r) {
            tile[(quad * 4 + r) * 136 + (w * 2) * 16 + l15] = f2bf(fmaxf(acc0[r] + bias0, 0.f));
            tile[(quad * 4 + r) * 136 + (w * 2 + 1) * 16 + l15] = f2bf(fmaxf(acc1[r] + bias1, 0.f));
        }
        __syncthreads();
        uint4 v = *(const uint4*)(tile + erow * 136 + ecol);
        *(uint4*)(a2 + (row0 + erow) * 128 + ecol) = v;
        const unsigned short* us = (const unsigned short*)&v;
#pragma unroll
        for (int j = 0; j < 8; ++j) { float f = bf2f(us[j]); sreg[j] += f; qreg[j] += f * f; }
        __syncthreads();
    }
#pragma unroll
    for (int j = 0; j < 8; ++j) {
        atomicAdd(&bn[ecol + j], sreg[j]);
        atomicAdd(&bn[128 + ecol + j], qreg[j]);
    }
    __syncthreads();
    atomicAdd(&slots[(size_t)(blockIdx.x & 63) * 256 + tid], bn[tid]);
}

__global__ __launch_bounds__(128) void k_fold2(const float* __restrict__ slots,
        const float* __restrict__ g2, const float* __restrict__ b2n,
        const float* __restrict__ W3, const float* __restrict__ b3,
        float* __restrict__ w3p, float* __restrict__ b3p) {
    __shared__ float red[128];
    const int tid = threadIdx.x;
    float S = 0.f, Q = 0.f;
    for (int s = 0; s < 64; ++s) { S += slots[s * 256 + tid]; Q += slots[s * 256 + 128 + tid]; }
    const float invE = 1.f / (float)N_EDGES;
    float mu = S * invE;
    float var = Q * invE - mu * mu;
    float scl = g2[tid] * rsqrtf(var + 1e-5f);
    float shf = b2n[tid] - mu * scl;
    w3p[tid] = W3[tid] * scl;
    red[tid] = W3[tid] * shf;
    __syncthreads();
    for (int st = 64; st > 0; st >>= 1) {
        if (tid < st) red[tid] += red[tid + st];
        __syncthreads();
    }
    if (tid == 0) b3p[0] = b3[0] + red[0];
}

// out = a2 . w3' + b3' : 4 threads per row, shuffle reduce.
__global__ __launch_bounds__(256) void k_L3(const unsigned short* __restrict__ a2,
        const float* __restrict__ w3p, const float* __restrict__ b3p, float* __restrict__ out) {
    __shared__ float wl[128];
    const int tid = threadIdx.x;
    if (tid < 128) wl[tid] = w3p[tid];
    __syncthreads();
    const size_t row = (size_t)blockIdx.x * 64 + (tid >> 2);
    const int c0 = (tid & 3) * 8;
    const unsigned short* rowp = a2 + row * 128 + c0;
    float s = 0.f;
#pragma unroll
    for (int i = 0; i < 4; ++i) {
        uint4 u = *(const uint4*)(rowp + i * 32);
        const unsigned short* us = (const unsigned short*)&u;
#pragma unroll
        for (int j = 0; j < 8; ++j) s += bf2f(us[j]) * wl[c0 + i * 32 + j];
    }
    s += __shfl_xor(s, 1);
    s += __shfl_xor(s, 2);
    if ((tid & 3) == 0) out[row] = s + b3p[0];
}

extern "C" void kernel_launch(void* const* d_in, const int* in_sizes, int n_in,
                              void* d_out, int out_size, void* d_ws, size_t ws_size,
                              hipStream_t stream) {
    (void)in_sizes; (void)n_in; (void)out_size; (void)ws_size;
    const float* h   = (const float*)d_in[0];
    const float* e   = (const float*)d_in[1];
    const int*   src = (const int*)d_in[2];
    const int*   dst = (const int*)d_in[3];
    const float* bn0_g = (const float*)d_in[4];
    const float* bn0_b = (const float*)d_in[5];
    const float* W1 = (const float*)d_in[6];
    const float* b1 = (const float*)d_in[7];
    const float* bn1_g = (const float*)d_in[8];
    const float* bn1_b = (const float*)d_in[9];
    const float* W2 = (const float*)d_in[10];
    const float* b2 = (const float*)d_in[11];
    const float* bn2_g = (const float*)d_in[12];
    const float* bn2_b = (const float*)d_in[13];
    const float* W3 = (const float*)d_in[14];
    const float* b3 = (const float*)d_in[15];

    char* ws = (char*)d_ws;
    size_t off = 0;
    auto alloc = [&](size_t bytes) { char* p = ws + off; off += (bytes + 255) & ~(size_t)255; return p; };
    int*   cnt_s = (int*)alloc((size_t)N_NODES * 4);
    int*   cnt_d = (int*)alloc((size_t)N_NODES * 4);
    float* bn0_sum = (float*)alloc(320 * 4);
    float* bn0_sq  = (float*)alloc(320 * 4);
    float* bn1_slots = (float*)alloc(64 * 512 * 4);
    float* bn2_slots = (float*)alloc(64 * 256 * 4);
    const size_t zero_end = off;
    float* scale0 = (float*)alloc(320 * 4);
    float* shift0 = (float*)alloc(320 * 4);
    unsigned short* W1s = (unsigned short*)alloc(256 * 128 * 2);
    unsigned short* W1d = (unsigned short*)alloc(256 * 128 * 2);
    unsigned short* W1e = (unsigned short*)alloc(256 * 64 * 2);
    float* b1p = (float*)alloc(256 * 4);
    unsigned short* W2p = (unsigned short*)alloc(128 * 256 * 2);
    float* b2p = (float*)alloc(128 * 4);
    float* w3p = (float*)alloc(128 * 4);
    float* b3p = (float*)alloc(4);
    unsigned short* Ps = (unsigned short*)alloc((size_t)N_NODES * 256 * 2);
    unsigned short* Pd = (unsigned short*)alloc((size_t)N_NODES * 256 * 2);
    unsigned short* a1 = (unsigned short*)alloc((size_t)N_EDGES * 256 * 2);
    unsigned short* a2 = (unsigned short*)alloc((size_t)N_EDGES * 128 * 2);

    hipMemsetAsync(d_ws, 0, zero_end, stream);
    k_hist<<<(N_EDGES + 255) / 256, 256, 0, stream>>>(src, dst, cnt_s, cnt_d);
    k_estats<<<512, 256, 0, stream>>>(e, bn0_sum, bn0_sq);
    k_hstats<<<200, 256, 0, stream>>>(h, cnt_s, cnt_d, bn0_sum, bn0_sq);
    k_fold0<<<1, 320, 0, stream>>>(bn0_sum, bn0_sq, bn0_g, bn0_b, scale0, shift0);
    k_foldW1<<<1, 320, 0, stream>>>(W1, b1, scale0, shift0, W1s, W1d, W1e, b1p);
    k_P<<<dim3(196, 2), 256, 0, stream>>>(h, W1s, W1d, Ps, Pd);
    k_L1<<<N_EDGES / 256, 256, 0, stream>>>(e, src, dst, Ps, Pd, W1e, b1p, a1, bn1_slots);
    k_fold1<<<1, 256, 0, stream>>>(bn1_slots, bn1_g, bn1_b, W2, b2, W2p, b2p);
    k_L2<<<N_EDGES / 256, 256, 0, stream>>>(a1, W2p, b2p, a2, bn2_slots);
    k_fold2<<<1, 128, 0, stream>>>(bn2_slots, bn2_g, bn2_b, W3, b3, w3p, b3p);
    k_L3<<<N_EDGES / 64, 256, 0, stream>>>(a2, w3p, b3p, (float*)d_out);
}